// Round 1
// baseline (128.324 us; speedup 1.0000x reference)
//
#include <hip/hip_runtime.h>
#include <math.h>

// ContentLoss: 61x61 Gaussian (sigma=1) depthwise conv w/ reflect pad on
// a,b [16,3,512,512] f32; channel-mean; MSE of difference -> scalar.
//
// Optimizations (all exact up to fp reorder + <1e-10 rel truncation):
//  - conv is linear & identical per channel: blur(mean_c(a-b)) once.
//  - separable: 1-D horizontal pass then 1-D vertical pass.
//  - sigma=1 => taps beyond |d|=6 are <2.3e-11 of center: radius 6,
//    normalized by the FULL 61-tap sum (matches reference normalization).

#define R 6
#define HW 512
#define NB 16
#define NPIX (16.0f * 512.0f * 512.0f)

struct GaussW { float w[R + 1]; };

// Pass 1: one block per (image,row). Fuse channel-diff + horizontal blur.
// 128 threads, float4 loads (16B/lane), LDS row with reflect halo.
__global__ __launch_bounds__(128) void cl_pass1(
    const float* __restrict__ A, const float* __restrict__ B,
    float* __restrict__ T, GaussW gw) {
  const int row  = blockIdx.x;        // 0 .. 16*512-1
  const int bimg = row >> 9;
  const int y    = row & (HW - 1);
  const int tid  = threadIdx.x;       // 0..127
  const int x    = tid << 2;          // 4 floats per thread

  __shared__ float e[HW + 2 * R];

  const size_t base = ((size_t)bimg * 3 * HW + y) * HW;  // channel 0 row
  float4 s = {0.f, 0.f, 0.f, 0.f};
#pragma unroll
  for (int c = 0; c < 3; ++c) {
    const float4 av = *reinterpret_cast<const float4*>(A + base + (size_t)c * HW * HW + x);
    const float4 bv = *reinterpret_cast<const float4*>(B + base + (size_t)c * HW * HW + x);
    s.x += av.x - bv.x;
    s.y += av.y - bv.y;
    s.z += av.z - bv.z;
    s.w += av.w - bv.w;
  }
  const float inv3 = 1.0f / 3.0f;
  e[R + x + 0] = s.x * inv3;
  e[R + x + 1] = s.y * inv3;
  e[R + x + 2] = s.z * inv3;
  e[R + x + 3] = s.w * inv3;
  __syncthreads();
  // reflect halo: x=-(1+t) -> 1+t ; x=512+t -> 510-t
  if (tid < R) {
    e[R - 1 - tid]    = e[R + 1 + tid];
    e[R + HW + tid]   = e[R + HW - 2 - tid];
  }
  __syncthreads();

  float4 o;
  float* op = &o.x;
#pragma unroll
  for (int k = 0; k < 4; ++k) {
    const int xi = R + x + k;
    float acc = gw.w[0] * e[xi];
#pragma unroll
    for (int d = 1; d <= R; ++d) acc += gw.w[d] * (e[xi - d] + e[xi + d]);
    op[k] = acc;
  }
  *reinterpret_cast<float4*>(T + (size_t)row * HW + x) = o;
}

// Pass 2: vertical blur + square + reduce.
// Block = 256 threads owns (image, 256-wide x-strip, 32-row y-chunk).
// Grid = 16 * 2 * 16 = 512 blocks.
__global__ __launch_bounds__(256) void cl_pass2(
    const float* __restrict__ T, float* __restrict__ out, GaussW gw) {
  const int bid  = blockIdx.x;
  const int bimg = bid >> 5;            // 32 blocks per image
  const int rem  = bid & 31;
  const int xs   = rem & 1;             // 2 x-strips of 256
  const int yc   = rem >> 1;            // 16 y-chunks of 32
  const int x    = (xs << 8) + threadIdx.x;
  const int y0   = yc << 5;

  const float* tb = T + (size_t)bimg * HW * HW;

  float acc = 0.f;
#pragma unroll 4
  for (int yy = 0; yy < 32; ++yy) {
    const int y = y0 + yy;
    float v = gw.w[0] * tb[(size_t)y * HW + x];
#pragma unroll
    for (int d = 1; d <= R; ++d) {
      int ym = y - d; ym = (ym < 0) ? -ym : ym;
      int yp = y + d; yp = (yp > HW - 1) ? (2 * (HW - 1) - yp) : yp;
      v += gw.w[d] * (tb[(size_t)ym * HW + x] + tb[(size_t)yp * HW + x]);
    }
    acc += v * v;
  }

  // block reduce: wave shuffle then LDS across the 4 waves
#pragma unroll
  for (int off = 32; off > 0; off >>= 1) acc += __shfl_down(acc, off, 64);
  __shared__ float wsum[4];
  const int lane = threadIdx.x & 63;
  const int wv   = threadIdx.x >> 6;
  if (lane == 0) wsum[wv] = acc;
  __syncthreads();
  if (threadIdx.x == 0) {
    const float s = wsum[0] + wsum[1] + wsum[2] + wsum[3];
    atomicAdd(out, s * (1.0f / NPIX));
  }
}

extern "C" void kernel_launch(void* const* d_in, const int* in_sizes, int n_in,
                              void* d_out, int out_size, void* d_ws, size_t ws_size,
                              hipStream_t stream) {
  const float* A = (const float*)d_in[0];
  const float* B = (const float*)d_in[1];
  float* out = (float*)d_out;
  float* T = (float*)d_ws;  // 16*512*512 floats = 16.8 MB

  // 1-D weights: w[d] = exp(-d^2/2) / sum_{x=0..60} exp(-(x-30)^2/2).
  // Normalizing by the FULL 61-tap sum matches the reference's k2/sum(k2).
  GaussW gw;
  {
    double S = 0.0;
    for (int i = 0; i < 61; ++i) {
      const double dd = (double)i - 30.0;
      S += exp(-dd * dd * 0.5);
    }
    for (int d = 0; d <= R; ++d)
      gw.w[d] = (float)(exp(-(double)(d * d) * 0.5) / S);
  }

  hipMemsetAsync(d_out, 0, sizeof(float), stream);
  cl_pass1<<<NB * HW, 128, 0, stream>>>(A, B, T, gw);
  cl_pass2<<<NB * 32, 256, 0, stream>>>(T, out, gw);
}